// Round 9
// baseline (236.168 us; speedup 1.0000x reference)
//
#include <hip/hip_runtime.h>
#include <hip/hip_fp16.h>

#define NN 100000
#define NE 1600000
#define SHIFT 8     // 256-node buckets (R4/R6 best; R5's 64-node and R7's 32-node both regressed)
#define NBUCK 391   // ceil(NN / 256)
#define P1B   1024  // edge-slice blocks
#define EPB   1563  // ceil(NE / P1B)

typedef _Float16 f16x8 __attribute__((ext_vector_type(8)));
typedef float f32x4 __attribute__((ext_vector_type(4)));
union H8U4 { f16x8 h; uint4 u; };

// 256-thread inclusive Hillis-Steele scan in LDS; returns inclusive value for this thread.
// sS[255] holds the chunk total afterwards.
__device__ __forceinline__ int scan256(int* s, int t, int v) {
    s[t] = v;
    __syncthreads();
    for (int off = 1; off < 256; off <<= 1) {
        int add = (t >= off) ? s[t - off] : 0;
        __syncthreads();
        s[t] += add;
        __syncthreads();
    }
    return s[t];
}

// ---------------- fused: f16 convert + weight prep + LDS histogram (per edge-slice) ----------------
// hist layout is [slice][bucket]: each block writes its 391-int histogram CONTIGUOUSLY
// (R5's [bucket][slice] column writes were the regression: 256 threads x 256 distinct 64B lines).
// No global atomics (R3: +50us/+54MB writeback), no bin_total, no memset.
__global__ __launch_bounds__(256) void k_hist(
    const float4* __restrict__ x4, ushort4* __restrict__ xh4,
    const float* __restrict__ Wl1, const float* __restrict__ Wr1, unsigned short* __restrict__ wt1,
    const float* __restrict__ Wl2, const float* __restrict__ Wr2, unsigned short* __restrict__ wt2,
    const int* __restrict__ dst, int* __restrict__ hist)
{
    __shared__ int h[NBUCK];
    int t = threadIdx.x, blk = blockIdx.x;

    const int n4 = NN * 16;
    const int per = (n4 + P1B - 1) / P1B;  // 1563
    int cb = blk * per, ce = min(cb + per, n4);
    for (int i = cb + t; i < ce; i += 256) {
        float4 f = x4[i];
        _Float16 a = (_Float16)f.x, b = (_Float16)f.y, c = (_Float16)f.z, d = (_Float16)f.w;
        ushort4 u;
        u.x = *(unsigned short*)&a; u.y = *(unsigned short*)&b;
        u.z = *(unsigned short*)&c; u.w = *(unsigned short*)&d;
        xh4[i] = u;
    }
    if (blk < 64) {  // blocks 0..31 -> wt1, 32..63 -> wt2
        int idx = (blk & 31) * 256 + t;  // 0..8191
        const float* Wl = (blk < 32) ? Wl1 : Wl2;
        const float* Wr = (blk < 32) ? Wr1 : Wr2;
        unsigned short* wt = (blk < 32) ? wt1 : wt2;
        int n = idx >> 7, k = idx & 127;
        float v = (k < 64) ? Wl[k * 64 + n] : Wr[(k - 64) * 64 + n];
        _Float16 hv = (_Float16)v;
        wt[idx] = *(unsigned short*)&hv;
    }

    for (int i = t; i < NBUCK; i += 256) h[i] = 0;
    __syncthreads();
    int eb = blk * EPB, ee = min(eb + EPB, NE);
    for (int e = eb + t; e < ee; e += 256) atomicAdd(&h[dst[e] >> SHIFT], 1);
    __syncthreads();
    for (int i = t; i < NBUCK; i += 256) hist[(size_t)blk * NBUCK + i] = h[i];  // contiguous row
}

// ---------------- per-bucket column scan: 1024 THREADS (R9 change, same class as R8's csr widen) -----
// Block b owns bucket b; thread t owns slice t. One strided load each (vs 4 serial at 256 threads),
// one 10-round Hillis-Steele scan across the 1024 slices. Work/output bit-identical to the 256-thread
// version; per-block latency ~4x lower (391 blocks = 1.5/CU was the last grid-starved kernel).
__global__ __launch_bounds__(1024) void k_colscan(int* __restrict__ hist, int* __restrict__ total,
                                                  int* __restrict__ offsets) {
    __shared__ int sS[1024];
    int b = blockIdx.x, t = threadIdx.x;
    int v = hist[(size_t)t * NBUCK + b];
    sS[t] = v;
    __syncthreads();
    for (int off = 1; off < 1024; off <<= 1) {
        int add = (t >= off) ? sS[t - off] : 0;
        __syncthreads();
        sS[t] += add;
        __syncthreads();
    }
    hist[(size_t)t * NBUCK + b] = sS[t] - v;  // exclusive prefix, in place
    if (t == 1023) total[b] = sS[1023];
    if (b == 0 && t == 0) offsets[NN] = NE;
}

// ---------------- scatter packed (src | (dst&255)<<17) into bucket order ----------------
// Bucket bases computed locally from total[] (LDS scan) -> no bucket_start array / kernel.
__global__ __launch_bounds__(256) void k_scatter(const int* __restrict__ src, const int* __restrict__ dst,
                                                 const int* __restrict__ hist, const int* __restrict__ total,
                                                 unsigned int* __restrict__ pairs) {
    __shared__ int cur[NBUCK];
    __shared__ int sS[256];
    int t = threadIdx.x, blk = blockIdx.x;
    int carry = 0;
#pragma unroll
    for (int c = 0; c < 2; c++) {
        int idx = c * 256 + t;
        int v = (idx < NBUCK) ? total[idx] : 0;
        int incl = scan256(sS, t, v);
        if (idx < NBUCK)
            cur[idx] = carry + incl - v + hist[(size_t)blk * NBUCK + idx];  // contiguous row read
        __syncthreads();
        carry += sS[255];
        __syncthreads();
    }
    int eb = blk * EPB, ee = min(eb + EPB, NE);
    for (int e = eb + t; e < ee; e += 256) {
        int d = dst[e];
        int pos = atomicAdd(&cur[d >> SHIFT], 1);
        pairs[pos] = (unsigned int)src[e] | ((unsigned int)(d & 255) << 17);
    }
}

// ---------------- per-bucket CSR finalize: 256 nodes/bucket, 1024 threads (R8 win: -10us) -----------
__global__ __launch_bounds__(1024) void k_bucket_csr(const unsigned int* __restrict__ pairs,
                                                     const int* __restrict__ total,
                                                     int* __restrict__ ssrc, int* __restrict__ offsets,
                                                     float* __restrict__ inv_deg) {
    __shared__ int sR[1024];
    __shared__ int cnt[256];
    __shared__ int cur[256];
    int b = blockIdx.x, t = threadIdx.x;
    // beg = sum of total[0..b-1] (1024-wide strided partials + tree reduce)
    int v = 0;
    for (int i = t; i < b; i += 1024) v += total[i];
    sR[t] = v;
    __syncthreads();
    for (int s = 512; s > 0; s >>= 1) {
        if (t < s) sR[t] += sR[t + s];
        __syncthreads();
    }
    int beg = sR[0];
    int end = beg + total[b];
    __syncthreads();
    if (t < 256) cnt[t] = 0;
    __syncthreads();
    for (int e = beg + t; e < end; e += 1024) atomicAdd(&cnt[pairs[e] >> 17], 1);
    __syncthreads();
    // inclusive scan of the 256 bins; all 1024 threads execute the barriers
    int deg = (t < 256) ? cnt[t] : 0;
    if (t < 256) sR[t] = deg;
    __syncthreads();
    for (int off = 1; off < 256; off <<= 1) {
        int add = (t < 256 && t >= off) ? sR[t - off] : 0;
        __syncthreads();
        if (t < 256) sR[t] += add;
        __syncthreads();
    }
    if (t < 256) {
        int incl = sR[t];
        int ex = incl - deg;
        int node = (b << SHIFT) + t;
        if (node < NN) {
            offsets[node] = beg + ex;
            inv_deg[node] = (deg > 0) ? (1.0f / (float)deg) : 0.0f;
        }
        cur[t] = beg + ex;  // cursor
    }
    __syncthreads();
    for (int e = beg + t; e < end; e += 1024) {
        unsigned int pr = pairs[e];
        int pos = atomicAdd(&cur[pr >> 17], 1);
        ssrc[pos] = (int)(pr & 0x1FFFFu);
    }
}

// ---------------- pair aggregation inner loop (identical numerics since R1) ----------
// Lane l: chunk c=l&7 (16B of f16x8), edge-slot g=l>>3 (8 slots shared by both nodes).
__device__ __forceinline__ void agg_pair(const uint4* __restrict__ featq, const int* __restrict__ ssrc,
                                         int beg0, int end0, int beg1, int end1,
                                         int c, int g, H8U4& acc0, H8U4& acc1) {
    int e0 = beg0, e1 = beg1;

    // joint main loop: 16 edges per node per iter -> 4 independent feature gathers in flight
    while (e0 + 16 <= end0 && e1 + 16 <= end1) {
        int i00 = ssrc[e0 + g], i01 = ssrc[e0 + 8 + g];
        int i10 = ssrc[e1 + g], i11 = ssrc[e1 + 8 + g];
        H8U4 q00, q01, q10, q11;
        q00.u = featq[(size_t)i00 * 8 + c];
        q01.u = featq[(size_t)i01 * 8 + c];
        q10.u = featq[(size_t)i10 * 8 + c];
        q11.u = featq[(size_t)i11 * 8 + c];
        acc0.h += q00.h; acc0.h += q01.h;
        acc1.h += q10.h; acc1.h += q11.h;
        e0 += 16; e1 += 16;
    }
    // drain node0
    for (; e0 + 16 <= end0; e0 += 16) {
        int i0 = ssrc[e0 + g], i1 = ssrc[e0 + 8 + g];
        H8U4 q0, q1;
        q0.u = featq[(size_t)i0 * 8 + c];
        q1.u = featq[(size_t)i1 * 8 + c];
        acc0.h += q0.h; acc0.h += q1.h;
    }
    for (; e0 < end0; e0 += 8) {
        int m = end0 - e0;
        int idx = ssrc[e0 + (g < m ? g : m - 1)];
        H8U4 q;
        q.u = featq[(size_t)idx * 8 + c];
        if (g < m) acc0.h += q.h;
    }
    // drain node1
    for (; e1 + 16 <= end1; e1 += 16) {
        int i0 = ssrc[e1 + g], i1 = ssrc[e1 + 8 + g];
        H8U4 q0, q1;
        q0.u = featq[(size_t)i0 * 8 + c];
        q1.u = featq[(size_t)i1 * 8 + c];
        acc1.h += q0.h; acc1.h += q1.h;
    }
    for (; e1 < end1; e1 += 8) {
        int m = end1 - e1;
        int idx = ssrc[e1 + (g < m ? g : m - 1)];
        H8U4 q;
        q.u = featq[(size_t)idx * 8 + c];
        if (g < m) acc1.h += q.h;
    }
}

// ---------------- fused layer: mean-aggregate (into LDS) + MFMA dual GEMM + relu (+ optional head) --------
// UNCHANGED from R4 (best measured 51.5-52us; R0/R2/R4 evidence: gather is miss-path saturated at
// ~82MB / ~1.9TB/s regardless of TLP/ILP -> structural floor for this access pattern).
template <bool FUSE_HEAD>
__global__ __launch_bounds__(256) void k_fused(const uint4* __restrict__ featq,  // gather source == root
                                               const int* __restrict__ ssrc,
                                               const int* __restrict__ offsets, const float* __restrict__ inv_deg,
                                               const uint4* __restrict__ wtq,   // WcatT f16 [64][128] as uint4
                                               const float* __restrict__ bias,
                                               const float* __restrict__ Wfc, const float* __restrict__ bfc,
                                               float* __restrict__ out_f32, unsigned short* __restrict__ out_f16) {
    // pad to 9 uint4/row: A-frag read spreads banks (2-way max, free); [32][8] would be 16-way.
    __shared__ uint4 sAgg[32][9];

    int tid = threadIdx.x;
    int wave = tid >> 6, lane = tid & 63;
    int base = blockIdx.x * 32;

    // ---- phase 1: aggregate 8 nodes (4 pairs) per wave ----
    {
        int c = lane & 7, g = lane >> 3;
#pragma unroll 1
        for (int p = 0; p < 4; ++p) {
            int l0 = wave * 8 + p * 2;
            int node0 = base + l0;
            int node1 = node0 + 1;
            if (node0 >= NN) {
                if (g == 0) {
                    uint4 z = {0u, 0u, 0u, 0u};
                    sAgg[l0][c] = z;
                    sAgg[l0 + 1][c] = z;
                }
                continue;
            }
            bool has1 = node1 < NN;
            int beg0 = offsets[node0], end0 = offsets[node0 + 1];
            int beg1 = has1 ? offsets[node1] : 0, end1 = has1 ? offsets[node1 + 1] : 0;
            H8U4 acc0, acc1;
            acc0.h = (f16x8)(_Float16)0;
            acc1.h = (f16x8)(_Float16)0;
            agg_pair(featq, ssrc, beg0, end0, beg1, end1, c, g, acc0, acc1);

            // fold 8 edge-slots (lanes differing in bits 3..5), both accumulators
#pragma unroll
            for (int mask = 8; mask <= 32; mask <<= 1) {
                H8U4 o0, o1;
                o0.u.x = __shfl_xor(acc0.u.x, mask); o0.u.y = __shfl_xor(acc0.u.y, mask);
                o0.u.z = __shfl_xor(acc0.u.z, mask); o0.u.w = __shfl_xor(acc0.u.w, mask);
                o1.u.x = __shfl_xor(acc1.u.x, mask); o1.u.y = __shfl_xor(acc1.u.y, mask);
                o1.u.z = __shfl_xor(acc1.u.z, mask); o1.u.w = __shfl_xor(acc1.u.w, mask);
                acc0.h += o0.h;
                acc1.h += o1.h;
            }

            if (g == 0) {
                float s0 = inv_deg[node0];
                H8U4 r;
#pragma unroll
                for (int j = 0; j < 8; j++) r.h[j] = (_Float16)((float)acc0.h[j] * s0);
                sAgg[l0][c] = r.u;
                H8U4 r1;
                if (has1) {
                    float s1 = inv_deg[node1];
#pragma unroll
                    for (int j = 0; j < 8; j++) r1.h[j] = (_Float16)((float)acc1.h[j] * s1);
                } else {
                    r1.u = (uint4){0u, 0u, 0u, 0u};
                }
                sAgg[l0 + 1][c] = r1.u;
            }
        }
    }
    __syncthreads();

    // ---- phase 2: dual GEMM relu([agg|root] @ WcatT^T + b), optional @Wfc+bfc head (waves 0-1) ----
    if (wave >= 2) return;

    int nb = base + wave * 16;
    int m = lane & 15, quad = lane >> 4;
    int l = wave * 16 + m;

    int an = nb + m;
    if (an > NN - 1) an = NN - 1;
    H8U4 a[4];
    a[0].u = sAgg[l][quad];
    a[1].u = sAgg[l][4 + quad];
    a[2].u = featq[(size_t)an * 8 + quad];
    a[3].u = featq[(size_t)an * 8 + 4 + quad];

    f32x4 acc[4];
#pragma unroll
    for (int n = 0; n < 4; n++) acc[n] = (f32x4){0.f, 0.f, 0.f, 0.f};

#pragma unroll
    for (int ncol = 0; ncol < 4; ncol++) {
        int col = ncol * 16 + m;
#pragma unroll
        for (int ki = 0; ki < 4; ki++) {
            H8U4 b;
            b.u = wtq[col * 16 + ki * 4 + quad];
            acc[ncol] = __builtin_amdgcn_mfma_f32_16x16x32_f16(a[ki].h, b.h, acc[ncol], 0, 0, 0);
        }
    }

    float bs[4];
#pragma unroll
    for (int ncol = 0; ncol < 4; ncol++) bs[ncol] = bias[ncol * 16 + m];

    if (!FUSE_HEAD) {
#pragma unroll
        for (int r = 0; r < 4; r++) {
            int node = nb + quad * 4 + r;
            if (node < NN) {
#pragma unroll
                for (int ncol = 0; ncol < 4; ncol++) {
                    float v = fmaxf(acc[ncol][r] + bs[ncol], 0.f);
                    _Float16 hv = (_Float16)v;
                    out_f16[(size_t)node * 64 + ncol * 16 + m] = *(unsigned short*)&hv;
                }
            }
        }
    } else {
        float wf[4];
#pragma unroll
        for (int ncol = 0; ncol < 4; ncol++) wf[ncol] = Wfc[ncol * 16 + m];
#pragma unroll
        for (int r = 0; r < 4; r++) {
            int node = nb + quad * 4 + r;
            float partial = 0.f;
#pragma unroll
            for (int ncol = 0; ncol < 4; ncol++)
                partial += fmaxf(acc[ncol][r] + bs[ncol], 0.f) * wf[ncol];
            partial += __shfl_xor(partial, 1);
            partial += __shfl_xor(partial, 2);
            partial += __shfl_xor(partial, 4);
            partial += __shfl_xor(partial, 8);
            if (m == 0 && node < NN) out_f32[node] = partial + bfc[0];
        }
    }
}

extern "C" void kernel_launch(void* const* d_in, const int* in_sizes, int n_in,
                              void* d_out, int out_size, void* d_ws, size_t ws_size,
                              hipStream_t stream) {
    const float* x   = (const float*)d_in[0];
    const int*   ei  = (const int*)d_in[1];
    const float* Wl1 = (const float*)d_in[2];
    const float* bl1 = (const float*)d_in[3];
    const float* Wr1 = (const float*)d_in[4];
    const float* Wl2 = (const float*)d_in[5];
    const float* bl2 = (const float*)d_in[6];
    const float* Wr2 = (const float*)d_in[7];
    const float* Wfc = (const float*)d_in[8];
    const float* bfc = (const float*)d_in[9];
    float* out = (float*)d_out;

    const int* srcp = ei;       // edge_index[0]
    const int* dstp = ei + NE;  // edge_index[1]

    char* p = (char*)d_ws;
    auto carve = [&](size_t bytes) {
        char* q = p;
        p += (bytes + 255) & ~size_t(255);
        return q;
    };
    int*            offsets = (int*)carve((size_t)(NN + 1) * 4);
    float*          inv_deg = (float*)carve((size_t)NN * 4);
    int*            ssrc    = (int*)carve((size_t)NE * 4);
    unsigned short* xh      = (unsigned short*)carve((size_t)NN * 64 * 2);
    unsigned short* h1h     = (unsigned short*)carve((size_t)NN * 64 * 2);
    unsigned short* wt1     = (unsigned short*)carve(64 * 128 * 2);
    unsigned short* wt2     = (unsigned short*)carve(64 * 128 * 2);
    unsigned int*   pairs   = (unsigned int*)carve((size_t)NE * 4);
    int*            hist    = (int*)carve((size_t)P1B * NBUCK * 4);   // [slice][bucket], 1.6 MB
    int*            total   = (int*)carve((size_t)NBUCK * 4);

    const int tile = (NN + 31) / 32;  // 3125 blocks of 32 nodes

    // graph build: 4 launches, no memset, no global atomics (R3: +50us), row-contiguous hist
    // (R5: column-layout hist was the regression; R7: merged sort-into-fused was the regression;
    // R8/R9: widen the grid-starved 391-block kernels to 1024 threads instead of restructuring).
    k_hist<<<P1B, 256, 0, stream>>>((const float4*)x, (ushort4*)xh,
                                    Wl1, Wr1, wt1, Wl2, Wr2, wt2, dstp, hist);
    k_colscan<<<NBUCK, 1024, 0, stream>>>(hist, total, offsets);
    k_scatter<<<P1B, 256, 0, stream>>>(srcp, dstp, hist, total, pairs);
    k_bucket_csr<<<NBUCK, 1024, 0, stream>>>(pairs, total, ssrc, offsets, inv_deg);

    // layer 1: fused gather-aggregate (LDS) + MFMA dual GEMM -> h1h (f16)
    k_fused<false><<<tile, 256, 0, stream>>>((const uint4*)xh, ssrc, offsets, inv_deg,
                                             (const uint4*)wt1, bl1, Wfc, bfc, nullptr, h1h);
    // layer 2 + fused head
    k_fused<true><<<tile, 256, 0, stream>>>((const uint4*)h1h, ssrc, offsets, inv_deg,
                                            (const uint4*)wt2, bl2, Wfc, bfc, out, nullptr);
}

// Round 10
// 227.938 us; speedup vs baseline: 1.0361x; 1.0361x over previous
//
#include <hip/hip_runtime.h>
#include <hip/hip_fp16.h>

#define NN 100000
#define NE 1600000
#define SHIFT 8     // 256-node buckets (R4/R6 best; R5's 64-node and R7's 32-node both regressed)
#define NBUCK 391   // ceil(NN / 256)
#define P1B   1024  // edge-slice blocks
#define EPB   1563  // ceil(NE / P1B)

typedef _Float16 f16x8 __attribute__((ext_vector_type(8)));
typedef float f32x4 __attribute__((ext_vector_type(4)));
union H8U4 { f16x8 h; uint4 u; };

// 256-thread inclusive Hillis-Steele scan in LDS; returns inclusive value for this thread.
// sS[255] holds the chunk total afterwards.
__device__ __forceinline__ int scan256(int* s, int t, int v) {
    s[t] = v;
    __syncthreads();
    for (int off = 1; off < 256; off <<= 1) {
        int add = (t >= off) ? s[t - off] : 0;
        __syncthreads();
        s[t] += add;
        __syncthreads();
    }
    return s[t];
}

// ---------------- fused: f16 convert + weight prep + LDS histogram (per edge-slice) ----------------
// hist layout is [slice][bucket]: each block writes its 391-int histogram CONTIGUOUSLY
// (R5's [bucket][slice] column writes were the regression: 256 threads x 256 distinct 64B lines).
// No global atomics (R3: +50us/+54MB writeback), no bin_total, no memset.
__global__ __launch_bounds__(256) void k_hist(
    const float4* __restrict__ x4, ushort4* __restrict__ xh4,
    const float* __restrict__ Wl1, const float* __restrict__ Wr1, unsigned short* __restrict__ wt1,
    const float* __restrict__ Wl2, const float* __restrict__ Wr2, unsigned short* __restrict__ wt2,
    const int* __restrict__ dst, int* __restrict__ hist)
{
    __shared__ int h[NBUCK];
    int t = threadIdx.x, blk = blockIdx.x;

    const int n4 = NN * 16;
    const int per = (n4 + P1B - 1) / P1B;  // 1563
    int cb = blk * per, ce = min(cb + per, n4);
    for (int i = cb + t; i < ce; i += 256) {
        float4 f = x4[i];
        _Float16 a = (_Float16)f.x, b = (_Float16)f.y, c = (_Float16)f.z, d = (_Float16)f.w;
        ushort4 u;
        u.x = *(unsigned short*)&a; u.y = *(unsigned short*)&b;
        u.z = *(unsigned short*)&c; u.w = *(unsigned short*)&d;
        xh4[i] = u;
    }
    if (blk < 64) {  // blocks 0..31 -> wt1, 32..63 -> wt2
        int idx = (blk & 31) * 256 + t;  // 0..8191
        const float* Wl = (blk < 32) ? Wl1 : Wl2;
        const float* Wr = (blk < 32) ? Wr1 : Wr2;
        unsigned short* wt = (blk < 32) ? wt1 : wt2;
        int n = idx >> 7, k = idx & 127;
        float v = (k < 64) ? Wl[k * 64 + n] : Wr[(k - 64) * 64 + n];
        _Float16 hv = (_Float16)v;
        wt[idx] = *(unsigned short*)&hv;
    }

    for (int i = t; i < NBUCK; i += 256) h[i] = 0;
    __syncthreads();
    int eb = blk * EPB, ee = min(eb + EPB, NE);
    for (int e = eb + t; e < ee; e += 256) atomicAdd(&h[dst[e] >> SHIFT], 1);
    __syncthreads();
    for (int i = t; i < NBUCK; i += 256) hist[(size_t)blk * NBUCK + i] = h[i];  // contiguous row
}

// ---------------- per-bucket column scan: exclusive prefix across the 1024 slices, in place ----------
// Block b owns bucket b. Strided reads (stride NBUCK*4 = 1.5KB) but adjacent blocks share each 64B
// line 16:1 -> L2-served. Emits per-bucket total. (R8 form; R9's 1024-thread widen was noise-neutral.)
__global__ __launch_bounds__(256) void k_colscan(int* __restrict__ hist, int* __restrict__ total,
                                                 int* __restrict__ offsets) {
    __shared__ int sS[256];
    int b = blockIdx.x, t = threadIdx.x;
    int v0 = hist[(size_t)(t * 4 + 0) * NBUCK + b];
    int v1 = hist[(size_t)(t * 4 + 1) * NBUCK + b];
    int v2 = hist[(size_t)(t * 4 + 2) * NBUCK + b];
    int v3 = hist[(size_t)(t * 4 + 3) * NBUCK + b];
    int s = v0 + v1 + v2 + v3;
    int incl = scan256(sS, t, s);
    int ex = incl - s;
    hist[(size_t)(t * 4 + 0) * NBUCK + b] = ex;
    hist[(size_t)(t * 4 + 1) * NBUCK + b] = ex + v0;
    hist[(size_t)(t * 4 + 2) * NBUCK + b] = ex + v0 + v1;
    hist[(size_t)(t * 4 + 3) * NBUCK + b] = ex + v0 + v1 + v2;
    if (t == 255) total[b] = incl;
    if (b == 0 && t == 0) offsets[NN] = NE;
}

// ---------------- scatter packed (src | (dst&255)<<17) into bucket order ----------------
// R10 change: XCD-AFFINE SLICE REMAP. Default dispatch puts consecutive blockIdx (= consecutive
// slices = adjacent cursor positions in every bucket segment) on DIFFERENT XCDs, so each 64B pairs
// line is dirtied alternately by all 8 per-XCD L2s (same cross-XCD line ping-pong R3 measured at
// +54MB/+50us). Remap block bid -> slice ((bid&7)<<7)|(bid>>3): each XCD handles 128 CONSECUTIVE
// slices, so each bucket segment is written in contiguous runs by ONE L2 -> lines dirtied once.
// pairs content is bit-identical (cursor windows are precomputed from the colscan prefix).
__global__ __launch_bounds__(256) void k_scatter(const int* __restrict__ src, const int* __restrict__ dst,
                                                 const int* __restrict__ hist, const int* __restrict__ total,
                                                 unsigned int* __restrict__ pairs) {
    __shared__ int cur[NBUCK];
    __shared__ int sS[256];
    int t = threadIdx.x;
    int bid = blockIdx.x;
    int blk = ((bid & 7) << 7) | (bid >> 3);  // slice index: XCD (bid&7) owns slices [xcd*128, xcd*128+128)
    int carry = 0;
#pragma unroll
    for (int c = 0; c < 2; c++) {
        int idx = c * 256 + t;
        int v = (idx < NBUCK) ? total[idx] : 0;
        int incl = scan256(sS, t, v);
        if (idx < NBUCK)
            cur[idx] = carry + incl - v + hist[(size_t)blk * NBUCK + idx];  // contiguous row read
        __syncthreads();
        carry += sS[255];
        __syncthreads();
    }
    int eb = blk * EPB, ee = min(eb + EPB, NE);
    for (int e = eb + t; e < ee; e += 256) {
        int d = dst[e];
        int pos = atomicAdd(&cur[d >> SHIFT], 1);
        pairs[pos] = (unsigned int)src[e] | ((unsigned int)(d & 255) << 17);
    }
}

// ---------------- per-bucket CSR finalize: 256 nodes/bucket, 1024 threads (R8 win: -10us) -----------
__global__ __launch_bounds__(1024) void k_bucket_csr(const unsigned int* __restrict__ pairs,
                                                     const int* __restrict__ total,
                                                     int* __restrict__ ssrc, int* __restrict__ offsets,
                                                     float* __restrict__ inv_deg) {
    __shared__ int sR[1024];
    __shared__ int cnt[256];
    __shared__ int cur[256];
    int b = blockIdx.x, t = threadIdx.x;
    // beg = sum of total[0..b-1] (1024-wide strided partials + tree reduce)
    int v = 0;
    for (int i = t; i < b; i += 1024) v += total[i];
    sR[t] = v;
    __syncthreads();
    for (int s = 512; s > 0; s >>= 1) {
        if (t < s) sR[t] += sR[t + s];
        __syncthreads();
    }
    int beg = sR[0];
    int end = beg + total[b];
    __syncthreads();
    if (t < 256) cnt[t] = 0;
    __syncthreads();
    for (int e = beg + t; e < end; e += 1024) atomicAdd(&cnt[pairs[e] >> 17], 1);
    __syncthreads();
    // inclusive scan of the 256 bins; all 1024 threads execute the barriers
    int deg = (t < 256) ? cnt[t] : 0;
    if (t < 256) sR[t] = deg;
    __syncthreads();
    for (int off = 1; off < 256; off <<= 1) {
        int add = (t < 256 && t >= off) ? sR[t - off] : 0;
        __syncthreads();
        if (t < 256) sR[t] += add;
        __syncthreads();
    }
    if (t < 256) {
        int incl = sR[t];
        int ex = incl - deg;
        int node = (b << SHIFT) + t;
        if (node < NN) {
            offsets[node] = beg + ex;
            inv_deg[node] = (deg > 0) ? (1.0f / (float)deg) : 0.0f;
        }
        cur[t] = beg + ex;  // cursor
    }
    __syncthreads();
    for (int e = beg + t; e < end; e += 1024) {
        unsigned int pr = pairs[e];
        int pos = atomicAdd(&cur[pr >> 17], 1);
        ssrc[pos] = (int)(pr & 0x1FFFFu);
    }
}

// ---------------- pair aggregation inner loop (identical numerics since R1) ----------
// Lane l: chunk c=l&7 (16B of f16x8), edge-slot g=l>>3 (8 slots shared by both nodes).
__device__ __forceinline__ void agg_pair(const uint4* __restrict__ featq, const int* __restrict__ ssrc,
                                         int beg0, int end0, int beg1, int end1,
                                         int c, int g, H8U4& acc0, H8U4& acc1) {
    int e0 = beg0, e1 = beg1;

    // joint main loop: 16 edges per node per iter -> 4 independent feature gathers in flight
    while (e0 + 16 <= end0 && e1 + 16 <= end1) {
        int i00 = ssrc[e0 + g], i01 = ssrc[e0 + 8 + g];
        int i10 = ssrc[e1 + g], i11 = ssrc[e1 + 8 + g];
        H8U4 q00, q01, q10, q11;
        q00.u = featq[(size_t)i00 * 8 + c];
        q01.u = featq[(size_t)i01 * 8 + c];
        q10.u = featq[(size_t)i10 * 8 + c];
        q11.u = featq[(size_t)i11 * 8 + c];
        acc0.h += q00.h; acc0.h += q01.h;
        acc1.h += q10.h; acc1.h += q11.h;
        e0 += 16; e1 += 16;
    }
    // drain node0
    for (; e0 + 16 <= end0; e0 += 16) {
        int i0 = ssrc[e0 + g], i1 = ssrc[e0 + 8 + g];
        H8U4 q0, q1;
        q0.u = featq[(size_t)i0 * 8 + c];
        q1.u = featq[(size_t)i1 * 8 + c];
        acc0.h += q0.h; acc0.h += q1.h;
    }
    for (; e0 < end0; e0 += 8) {
        int m = end0 - e0;
        int idx = ssrc[e0 + (g < m ? g : m - 1)];
        H8U4 q;
        q.u = featq[(size_t)idx * 8 + c];
        if (g < m) acc0.h += q.h;
    }
    // drain node1
    for (; e1 + 16 <= end1; e1 += 16) {
        int i0 = ssrc[e1 + g], i1 = ssrc[e1 + 8 + g];
        H8U4 q0, q1;
        q0.u = featq[(size_t)i0 * 8 + c];
        q1.u = featq[(size_t)i1 * 8 + c];
        acc1.h += q0.h; acc1.h += q1.h;
    }
    for (; e1 < end1; e1 += 8) {
        int m = end1 - e1;
        int idx = ssrc[e1 + (g < m ? g : m - 1)];
        H8U4 q;
        q.u = featq[(size_t)idx * 8 + c];
        if (g < m) acc1.h += q.h;
    }
}

// ---------------- fused layer: mean-aggregate (into LDS) + MFMA dual GEMM + relu (+ optional head) --------
// UNCHANGED from R4 (best measured 51.5-52us; R0/R2/R4 evidence: gather is miss-path saturated at
// ~82MB / ~1.9TB/s regardless of TLP/ILP -> structural floor for this access pattern).
template <bool FUSE_HEAD>
__global__ __launch_bounds__(256) void k_fused(const uint4* __restrict__ featq,  // gather source == root
                                               const int* __restrict__ ssrc,
                                               const int* __restrict__ offsets, const float* __restrict__ inv_deg,
                                               const uint4* __restrict__ wtq,   // WcatT f16 [64][128] as uint4
                                               const float* __restrict__ bias,
                                               const float* __restrict__ Wfc, const float* __restrict__ bfc,
                                               float* __restrict__ out_f32, unsigned short* __restrict__ out_f16) {
    // pad to 9 uint4/row: A-frag read spreads banks (2-way max, free); [32][8] would be 16-way.
    __shared__ uint4 sAgg[32][9];

    int tid = threadIdx.x;
    int wave = tid >> 6, lane = tid & 63;
    int base = blockIdx.x * 32;

    // ---- phase 1: aggregate 8 nodes (4 pairs) per wave ----
    {
        int c = lane & 7, g = lane >> 3;
#pragma unroll 1
        for (int p = 0; p < 4; ++p) {
            int l0 = wave * 8 + p * 2;
            int node0 = base + l0;
            int node1 = node0 + 1;
            if (node0 >= NN) {
                if (g == 0) {
                    uint4 z = {0u, 0u, 0u, 0u};
                    sAgg[l0][c] = z;
                    sAgg[l0 + 1][c] = z;
                }
                continue;
            }
            bool has1 = node1 < NN;
            int beg0 = offsets[node0], end0 = offsets[node0 + 1];
            int beg1 = has1 ? offsets[node1] : 0, end1 = has1 ? offsets[node1 + 1] : 0;
            H8U4 acc0, acc1;
            acc0.h = (f16x8)(_Float16)0;
            acc1.h = (f16x8)(_Float16)0;
            agg_pair(featq, ssrc, beg0, end0, beg1, end1, c, g, acc0, acc1);

            // fold 8 edge-slots (lanes differing in bits 3..5), both accumulators
#pragma unroll
            for (int mask = 8; mask <= 32; mask <<= 1) {
                H8U4 o0, o1;
                o0.u.x = __shfl_xor(acc0.u.x, mask); o0.u.y = __shfl_xor(acc0.u.y, mask);
                o0.u.z = __shfl_xor(acc0.u.z, mask); o0.u.w = __shfl_xor(acc0.u.w, mask);
                o1.u.x = __shfl_xor(acc1.u.x, mask); o1.u.y = __shfl_xor(acc1.u.y, mask);
                o1.u.z = __shfl_xor(acc1.u.z, mask); o1.u.w = __shfl_xor(acc1.u.w, mask);
                acc0.h += o0.h;
                acc1.h += o1.h;
            }

            if (g == 0) {
                float s0 = inv_deg[node0];
                H8U4 r;
#pragma unroll
                for (int j = 0; j < 8; j++) r.h[j] = (_Float16)((float)acc0.h[j] * s0);
                sAgg[l0][c] = r.u;
                H8U4 r1;
                if (has1) {
                    float s1 = inv_deg[node1];
#pragma unroll
                    for (int j = 0; j < 8; j++) r1.h[j] = (_Float16)((float)acc1.h[j] * s1);
                } else {
                    r1.u = (uint4){0u, 0u, 0u, 0u};
                }
                sAgg[l0 + 1][c] = r1.u;
            }
        }
    }
    __syncthreads();

    // ---- phase 2: dual GEMM relu([agg|root] @ WcatT^T + b), optional @Wfc+bfc head (waves 0-1) ----
    if (wave >= 2) return;

    int nb = base + wave * 16;
    int m = lane & 15, quad = lane >> 4;
    int l = wave * 16 + m;

    int an = nb + m;
    if (an > NN - 1) an = NN - 1;
    H8U4 a[4];
    a[0].u = sAgg[l][quad];
    a[1].u = sAgg[l][4 + quad];
    a[2].u = featq[(size_t)an * 8 + quad];
    a[3].u = featq[(size_t)an * 8 + 4 + quad];

    f32x4 acc[4];
#pragma unroll
    for (int n = 0; n < 4; n++) acc[n] = (f32x4){0.f, 0.f, 0.f, 0.f};

#pragma unroll
    for (int ncol = 0; ncol < 4; ncol++) {
        int col = ncol * 16 + m;
#pragma unroll
        for (int ki = 0; ki < 4; ki++) {
            H8U4 b;
            b.u = wtq[col * 16 + ki * 4 + quad];
            acc[ncol] = __builtin_amdgcn_mfma_f32_16x16x32_f16(a[ki].h, b.h, acc[ncol], 0, 0, 0);
        }
    }

    float bs[4];
#pragma unroll
    for (int ncol = 0; ncol < 4; ncol++) bs[ncol] = bias[ncol * 16 + m];

    if (!FUSE_HEAD) {
#pragma unroll
        for (int r = 0; r < 4; r++) {
            int node = nb + quad * 4 + r;
            if (node < NN) {
#pragma unroll
                for (int ncol = 0; ncol < 4; ncol++) {
                    float v = fmaxf(acc[ncol][r] + bs[ncol], 0.f);
                    _Float16 hv = (_Float16)v;
                    out_f16[(size_t)node * 64 + ncol * 16 + m] = *(unsigned short*)&hv;
                }
            }
        }
    } else {
        float wf[4];
#pragma unroll
        for (int ncol = 0; ncol < 4; ncol++) wf[ncol] = Wfc[ncol * 16 + m];
#pragma unroll
        for (int r = 0; r < 4; r++) {
            int node = nb + quad * 4 + r;
            float partial = 0.f;
#pragma unroll
            for (int ncol = 0; ncol < 4; ncol++)
                partial += fmaxf(acc[ncol][r] + bs[ncol], 0.f) * wf[ncol];
            partial += __shfl_xor(partial, 1);
            partial += __shfl_xor(partial, 2);
            partial += __shfl_xor(partial, 4);
            partial += __shfl_xor(partial, 8);
            if (m == 0 && node < NN) out_f32[node] = partial + bfc[0];
        }
    }
}

extern "C" void kernel_launch(void* const* d_in, const int* in_sizes, int n_in,
                              void* d_out, int out_size, void* d_ws, size_t ws_size,
                              hipStream_t stream) {
    const float* x   = (const float*)d_in[0];
    const int*   ei  = (const int*)d_in[1];
    const float* Wl1 = (const float*)d_in[2];
    const float* bl1 = (const float*)d_in[3];
    const float* Wr1 = (const float*)d_in[4];
    const float* Wl2 = (const float*)d_in[5];
    const float* bl2 = (const float*)d_in[6];
    const float* Wr2 = (const float*)d_in[7];
    const float* Wfc = (const float*)d_in[8];
    const float* bfc = (const float*)d_in[9];
    float* out = (float*)d_out;

    const int* srcp = ei;       // edge_index[0]
    const int* dstp = ei + NE;  // edge_index[1]

    char* p = (char*)d_ws;
    auto carve = [&](size_t bytes) {
        char* q = p;
        p += (bytes + 255) & ~size_t(255);
        return q;
    };
    int*            offsets = (int*)carve((size_t)(NN + 1) * 4);
    float*          inv_deg = (float*)carve((size_t)NN * 4);
    int*            ssrc    = (int*)carve((size_t)NE * 4);
    unsigned short* xh      = (unsigned short*)carve((size_t)NN * 64 * 2);
    unsigned short* h1h     = (unsigned short*)carve((size_t)NN * 64 * 2);
    unsigned short* wt1     = (unsigned short*)carve(64 * 128 * 2);
    unsigned short* wt2     = (unsigned short*)carve(64 * 128 * 2);
    unsigned int*   pairs   = (unsigned int*)carve((size_t)NE * 4);
    int*            hist    = (int*)carve((size_t)P1B * NBUCK * 4);   // [slice][bucket], 1.6 MB
    int*            total   = (int*)carve((size_t)NBUCK * 4);

    const int tile = (NN + 31) / 32;  // 3125 blocks of 32 nodes

    // graph build: 4 launches, no memset, no global atomics (R3: +50us), row-contiguous hist
    // (R5: column-layout hist was the regression; R7: merged sort-into-fused was the regression;
    // R8: widen grid-starved csr to 1024 threads (-10us); R9: colscan widen neutral;
    // R10: XCD-affine slice remap in scatter to kill cross-XCD pairs-line ping-pong).
    k_hist<<<P1B, 256, 0, stream>>>((const float4*)x, (ushort4*)xh,
                                    Wl1, Wr1, wt1, Wl2, Wr2, wt2, dstp, hist);
    k_colscan<<<NBUCK, 256, 0, stream>>>(hist, total, offsets);
    k_scatter<<<P1B, 256, 0, stream>>>(srcp, dstp, hist, total, pairs);
    k_bucket_csr<<<NBUCK, 1024, 0, stream>>>(pairs, total, ssrc, offsets, inv_deg);

    // layer 1: fused gather-aggregate (LDS) + MFMA dual GEMM -> h1h (f16)
    k_fused<false><<<tile, 256, 0, stream>>>((const uint4*)xh, ssrc, offsets, inv_deg,
                                             (const uint4*)wt1, bl1, Wfc, bfc, nullptr, h1h);
    // layer 2 + fused head
    k_fused<true><<<tile, 256, 0, stream>>>((const uint4*)h1h, ssrc, offsets, inv_deg,
                                            (const uint4*)wt2, bl2, Wfc, bfc, out, nullptr);
}

// Round 11
// 221.402 us; speedup vs baseline: 1.0667x; 1.0295x over previous
//
#include <hip/hip_runtime.h>
#include <hip/hip_fp16.h>

#define NN 100000
#define NE 1600000
#define SHIFT 8     // 256-node buckets (R4/R6 best; R5's 64-node and R7's 32-node both regressed)
#define NBUCK 391   // ceil(NN / 256)
#define P1B   1024  // edge-slice blocks
#define EPB   1563  // ceil(NE / P1B)

typedef _Float16 f16x8 __attribute__((ext_vector_type(8)));
typedef float f32x4 __attribute__((ext_vector_type(4)));
union H8U4 { f16x8 h; uint4 u; };

// 256-thread inclusive Hillis-Steele scan in LDS; returns inclusive value for this thread.
// sS[255] holds the chunk total afterwards.
__device__ __forceinline__ int scan256(int* s, int t, int v) {
    s[t] = v;
    __syncthreads();
    for (int off = 1; off < 256; off <<= 1) {
        int add = (t >= off) ? s[t - off] : 0;
        __syncthreads();
        s[t] += add;
        __syncthreads();
    }
    return s[t];
}

// ---------------- fused: f16 convert + weight prep + LDS histogram (per edge-slice) ----------------
// hist layout is [slice][bucket]: each block writes its 391-int histogram CONTIGUOUSLY
// (R5's [bucket][slice] column writes were the regression: 256 threads x 256 distinct 64B lines).
// No global atomics (R3: +50us/+54MB writeback), no bin_total, no memset.
__global__ __launch_bounds__(256) void k_hist(
    const float4* __restrict__ x4, ushort4* __restrict__ xh4,
    const float* __restrict__ Wl1, const float* __restrict__ Wr1, unsigned short* __restrict__ wt1,
    const float* __restrict__ Wl2, const float* __restrict__ Wr2, unsigned short* __restrict__ wt2,
    const int* __restrict__ dst, int* __restrict__ hist)
{
    __shared__ int h[NBUCK];
    int t = threadIdx.x, blk = blockIdx.x;

    const int n4 = NN * 16;
    const int per = (n4 + P1B - 1) / P1B;  // 1563
    int cb = blk * per, ce = min(cb + per, n4);
    for (int i = cb + t; i < ce; i += 256) {
        float4 f = x4[i];
        _Float16 a = (_Float16)f.x, b = (_Float16)f.y, c = (_Float16)f.z, d = (_Float16)f.w;
        ushort4 u;
        u.x = *(unsigned short*)&a; u.y = *(unsigned short*)&b;
        u.z = *(unsigned short*)&c; u.w = *(unsigned short*)&d;
        xh4[i] = u;
    }
    if (blk < 64) {  // blocks 0..31 -> wt1, 32..63 -> wt2
        int idx = (blk & 31) * 256 + t;  // 0..8191
        const float* Wl = (blk < 32) ? Wl1 : Wl2;
        const float* Wr = (blk < 32) ? Wr1 : Wr2;
        unsigned short* wt = (blk < 32) ? wt1 : wt2;
        int n = idx >> 7, k = idx & 127;
        float v = (k < 64) ? Wl[k * 64 + n] : Wr[(k - 64) * 64 + n];
        _Float16 hv = (_Float16)v;
        wt[idx] = *(unsigned short*)&hv;
    }

    for (int i = t; i < NBUCK; i += 256) h[i] = 0;
    __syncthreads();
    int eb = blk * EPB, ee = min(eb + EPB, NE);
    for (int e = eb + t; e < ee; e += 256) atomicAdd(&h[dst[e] >> SHIFT], 1);
    __syncthreads();
    for (int i = t; i < NBUCK; i += 256) hist[(size_t)blk * NBUCK + i] = h[i];  // contiguous row
}

// ---------------- per-bucket column scan: exclusive prefix across the 1024 slices, in place ----------
// R11 change: XCD-AFFINE BUCKET REMAP. Each 64B hist line holds 16 consecutive buckets, i.e. it is
// read AND written (in-place prefix) by 16 different blocks; default round-robin puts those on all
// 8 XCDs -> 8x read replication + write-back line ping-pong (same pathology class as R3/R10).
// Bijective remap b=(bid&7)*49+(bid>>3): XCD k owns ~49 CONSECUTIVE buckets, so each line is owned
// by 1 (boundary: 2) L2s. Output bit-identical (pure permutation of independent per-bucket work).
__global__ __launch_bounds__(256) void k_colscan(int* __restrict__ hist, int* __restrict__ total,
                                                 int* __restrict__ offsets) {
    __shared__ int sS[256];
    int bid = blockIdx.x, t = threadIdx.x;
    int b = (bid & 7) * 49 + (bid >> 3);  // bijective on [0,391): xcd<7 own 49 buckets, xcd 7 owns 48
    int v0 = hist[(size_t)(t * 4 + 0) * NBUCK + b];
    int v1 = hist[(size_t)(t * 4 + 1) * NBUCK + b];
    int v2 = hist[(size_t)(t * 4 + 2) * NBUCK + b];
    int v3 = hist[(size_t)(t * 4 + 3) * NBUCK + b];
    int s = v0 + v1 + v2 + v3;
    int incl = scan256(sS, t, s);
    int ex = incl - s;
    hist[(size_t)(t * 4 + 0) * NBUCK + b] = ex;
    hist[(size_t)(t * 4 + 1) * NBUCK + b] = ex + v0;
    hist[(size_t)(t * 4 + 2) * NBUCK + b] = ex + v0 + v1;
    hist[(size_t)(t * 4 + 3) * NBUCK + b] = ex + v0 + v1 + v2;
    if (t == 255) total[b] = incl;
    if (bid == 0 && t == 0) offsets[NN] = NE;
}

// ---------------- scatter packed (src | (dst&255)<<17) into bucket order ----------------
// R10: XCD-affine slice remap (-7us): block bid -> slice ((bid&7)<<7)|(bid>>3) so each XCD handles
// 128 CONSECUTIVE slices and each bucket segment of pairs is written in contiguous runs by ONE L2.
__global__ __launch_bounds__(256) void k_scatter(const int* __restrict__ src, const int* __restrict__ dst,
                                                 const int* __restrict__ hist, const int* __restrict__ total,
                                                 unsigned int* __restrict__ pairs) {
    __shared__ int cur[NBUCK];
    __shared__ int sS[256];
    int t = threadIdx.x;
    int bid = blockIdx.x;
    int blk = ((bid & 7) << 7) | (bid >> 3);  // slice index: XCD (bid&7) owns slices [xcd*128, xcd*128+128)
    int carry = 0;
#pragma unroll
    for (int c = 0; c < 2; c++) {
        int idx = c * 256 + t;
        int v = (idx < NBUCK) ? total[idx] : 0;
        int incl = scan256(sS, t, v);
        if (idx < NBUCK)
            cur[idx] = carry + incl - v + hist[(size_t)blk * NBUCK + idx];  // contiguous row read
        __syncthreads();
        carry += sS[255];
        __syncthreads();
    }
    int eb = blk * EPB, ee = min(eb + EPB, NE);
    for (int e = eb + t; e < ee; e += 256) {
        int d = dst[e];
        int pos = atomicAdd(&cur[d >> SHIFT], 1);
        pairs[pos] = (unsigned int)src[e] | ((unsigned int)(d & 255) << 17);
    }
}

// ---------------- per-bucket CSR finalize: 256 nodes/bucket, 1024 threads (R8 win: -10us) -----------
__global__ __launch_bounds__(1024) void k_bucket_csr(const unsigned int* __restrict__ pairs,
                                                     const int* __restrict__ total,
                                                     int* __restrict__ ssrc, int* __restrict__ offsets,
                                                     float* __restrict__ inv_deg) {
    __shared__ int sR[1024];
    __shared__ int cnt[256];
    __shared__ int cur[256];
    int b = blockIdx.x, t = threadIdx.x;
    // beg = sum of total[0..b-1] (1024-wide strided partials + tree reduce)
    int v = 0;
    for (int i = t; i < b; i += 1024) v += total[i];
    sR[t] = v;
    __syncthreads();
    for (int s = 512; s > 0; s >>= 1) {
        if (t < s) sR[t] += sR[t + s];
        __syncthreads();
    }
    int beg = sR[0];
    int end = beg + total[b];
    __syncthreads();
    if (t < 256) cnt[t] = 0;
    __syncthreads();
    for (int e = beg + t; e < end; e += 1024) atomicAdd(&cnt[pairs[e] >> 17], 1);
    __syncthreads();
    // inclusive scan of the 256 bins; all 1024 threads execute the barriers
    int deg = (t < 256) ? cnt[t] : 0;
    if (t < 256) sR[t] = deg;
    __syncthreads();
    for (int off = 1; off < 256; off <<= 1) {
        int add = (t < 256 && t >= off) ? sR[t - off] : 0;
        __syncthreads();
        if (t < 256) sR[t] += add;
        __syncthreads();
    }
    if (t < 256) {
        int incl = sR[t];
        int ex = incl - deg;
        int node = (b << SHIFT) + t;
        if (node < NN) {
            offsets[node] = beg + ex;
            inv_deg[node] = (deg > 0) ? (1.0f / (float)deg) : 0.0f;
        }
        cur[t] = beg + ex;  // cursor
    }
    __syncthreads();
    for (int e = beg + t; e < end; e += 1024) {
        unsigned int pr = pairs[e];
        int pos = atomicAdd(&cur[pr >> 17], 1);
        ssrc[pos] = (int)(pr & 0x1FFFFu);
    }
}

// ---------------- pair aggregation inner loop (identical numerics since R1) ----------
// Lane l: chunk c=l&7 (16B of f16x8), edge-slot g=l>>3 (8 slots shared by both nodes).
__device__ __forceinline__ void agg_pair(const uint4* __restrict__ featq, const int* __restrict__ ssrc,
                                         int beg0, int end0, int beg1, int end1,
                                         int c, int g, H8U4& acc0, H8U4& acc1) {
    int e0 = beg0, e1 = beg1;

    // joint main loop: 16 edges per node per iter -> 4 independent feature gathers in flight
    while (e0 + 16 <= end0 && e1 + 16 <= end1) {
        int i00 = ssrc[e0 + g], i01 = ssrc[e0 + 8 + g];
        int i10 = ssrc[e1 + g], i11 = ssrc[e1 + 8 + g];
        H8U4 q00, q01, q10, q11;
        q00.u = featq[(size_t)i00 * 8 + c];
        q01.u = featq[(size_t)i01 * 8 + c];
        q10.u = featq[(size_t)i10 * 8 + c];
        q11.u = featq[(size_t)i11 * 8 + c];
        acc0.h += q00.h; acc0.h += q01.h;
        acc1.h += q10.h; acc1.h += q11.h;
        e0 += 16; e1 += 16;
    }
    // drain node0
    for (; e0 + 16 <= end0; e0 += 16) {
        int i0 = ssrc[e0 + g], i1 = ssrc[e0 + 8 + g];
        H8U4 q0, q1;
        q0.u = featq[(size_t)i0 * 8 + c];
        q1.u = featq[(size_t)i1 * 8 + c];
        acc0.h += q0.h; acc0.h += q1.h;
    }
    for (; e0 < end0; e0 += 8) {
        int m = end0 - e0;
        int idx = ssrc[e0 + (g < m ? g : m - 1)];
        H8U4 q;
        q.u = featq[(size_t)idx * 8 + c];
        if (g < m) acc0.h += q.h;
    }
    // drain node1
    for (; e1 + 16 <= end1; e1 += 16) {
        int i0 = ssrc[e1 + g], i1 = ssrc[e1 + 8 + g];
        H8U4 q0, q1;
        q0.u = featq[(size_t)i0 * 8 + c];
        q1.u = featq[(size_t)i1 * 8 + c];
        acc1.h += q0.h; acc1.h += q1.h;
    }
    for (; e1 < end1; e1 += 8) {
        int m = end1 - e1;
        int idx = ssrc[e1 + (g < m ? g : m - 1)];
        H8U4 q;
        q.u = featq[(size_t)idx * 8 + c];
        if (g < m) acc1.h += q.h;
    }
}

// ---------------- fused layer: mean-aggregate (into LDS) + MFMA dual GEMM + relu (+ optional head) --------
// UNCHANGED from R4 (best measured 51.5-52us; R0/R2/R4 evidence: gather is miss-path saturated at
// ~82MB / ~1.9TB/s regardless of TLP/ILP -> structural floor for this access pattern).
template <bool FUSE_HEAD>
__global__ __launch_bounds__(256) void k_fused(const uint4* __restrict__ featq,  // gather source == root
                                               const int* __restrict__ ssrc,
                                               const int* __restrict__ offsets, const float* __restrict__ inv_deg,
                                               const uint4* __restrict__ wtq,   // WcatT f16 [64][128] as uint4
                                               const float* __restrict__ bias,
                                               const float* __restrict__ Wfc, const float* __restrict__ bfc,
                                               float* __restrict__ out_f32, unsigned short* __restrict__ out_f16) {
    // pad to 9 uint4/row: A-frag read spreads banks (2-way max, free); [32][8] would be 16-way.
    __shared__ uint4 sAgg[32][9];

    int tid = threadIdx.x;
    int wave = tid >> 6, lane = tid & 63;
    int base = blockIdx.x * 32;

    // ---- phase 1: aggregate 8 nodes (4 pairs) per wave ----
    {
        int c = lane & 7, g = lane >> 3;
#pragma unroll 1
        for (int p = 0; p < 4; ++p) {
            int l0 = wave * 8 + p * 2;
            int node0 = base + l0;
            int node1 = node0 + 1;
            if (node0 >= NN) {
                if (g == 0) {
                    uint4 z = {0u, 0u, 0u, 0u};
                    sAgg[l0][c] = z;
                    sAgg[l0 + 1][c] = z;
                }
                continue;
            }
            bool has1 = node1 < NN;
            int beg0 = offsets[node0], end0 = offsets[node0 + 1];
            int beg1 = has1 ? offsets[node1] : 0, end1 = has1 ? offsets[node1 + 1] : 0;
            H8U4 acc0, acc1;
            acc0.h = (f16x8)(_Float16)0;
            acc1.h = (f16x8)(_Float16)0;
            agg_pair(featq, ssrc, beg0, end0, beg1, end1, c, g, acc0, acc1);

            // fold 8 edge-slots (lanes differing in bits 3..5), both accumulators
#pragma unroll
            for (int mask = 8; mask <= 32; mask <<= 1) {
                H8U4 o0, o1;
                o0.u.x = __shfl_xor(acc0.u.x, mask); o0.u.y = __shfl_xor(acc0.u.y, mask);
                o0.u.z = __shfl_xor(acc0.u.z, mask); o0.u.w = __shfl_xor(acc0.u.w, mask);
                o1.u.x = __shfl_xor(acc1.u.x, mask); o1.u.y = __shfl_xor(acc1.u.y, mask);
                o1.u.z = __shfl_xor(acc1.u.z, mask); o1.u.w = __shfl_xor(acc1.u.w, mask);
                acc0.h += o0.h;
                acc1.h += o1.h;
            }

            if (g == 0) {
                float s0 = inv_deg[node0];
                H8U4 r;
#pragma unroll
                for (int j = 0; j < 8; j++) r.h[j] = (_Float16)((float)acc0.h[j] * s0);
                sAgg[l0][c] = r.u;
                H8U4 r1;
                if (has1) {
                    float s1 = inv_deg[node1];
#pragma unroll
                    for (int j = 0; j < 8; j++) r1.h[j] = (_Float16)((float)acc1.h[j] * s1);
                } else {
                    r1.u = (uint4){0u, 0u, 0u, 0u};
                }
                sAgg[l0 + 1][c] = r1.u;
            }
        }
    }
    __syncthreads();

    // ---- phase 2: dual GEMM relu([agg|root] @ WcatT^T + b), optional @Wfc+bfc head (waves 0-1) ----
    if (wave >= 2) return;

    int nb = base + wave * 16;
    int m = lane & 15, quad = lane >> 4;
    int l = wave * 16 + m;

    int an = nb + m;
    if (an > NN - 1) an = NN - 1;
    H8U4 a[4];
    a[0].u = sAgg[l][quad];
    a[1].u = sAgg[l][4 + quad];
    a[2].u = featq[(size_t)an * 8 + quad];
    a[3].u = featq[(size_t)an * 8 + 4 + quad];

    f32x4 acc[4];
#pragma unroll
    for (int n = 0; n < 4; n++) acc[n] = (f32x4){0.f, 0.f, 0.f, 0.f};

#pragma unroll
    for (int ncol = 0; ncol < 4; ncol++) {
        int col = ncol * 16 + m;
#pragma unroll
        for (int ki = 0; ki < 4; ki++) {
            H8U4 b;
            b.u = wtq[col * 16 + ki * 4 + quad];
            acc[ncol] = __builtin_amdgcn_mfma_f32_16x16x32_f16(a[ki].h, b.h, acc[ncol], 0, 0, 0);
        }
    }

    float bs[4];
#pragma unroll
    for (int ncol = 0; ncol < 4; ncol++) bs[ncol] = bias[ncol * 16 + m];

    if (!FUSE_HEAD) {
#pragma unroll
        for (int r = 0; r < 4; r++) {
            int node = nb + quad * 4 + r;
            if (node < NN) {
#pragma unroll
                for (int ncol = 0; ncol < 4; ncol++) {
                    float v = fmaxf(acc[ncol][r] + bs[ncol], 0.f);
                    _Float16 hv = (_Float16)v;
                    out_f16[(size_t)node * 64 + ncol * 16 + m] = *(unsigned short*)&hv;
                }
            }
        }
    } else {
        float wf[4];
#pragma unroll
        for (int ncol = 0; ncol < 4; ncol++) wf[ncol] = Wfc[ncol * 16 + m];
#pragma unroll
        for (int r = 0; r < 4; r++) {
            int node = nb + quad * 4 + r;
            float partial = 0.f;
#pragma unroll
            for (int ncol = 0; ncol < 4; ncol++)
                partial += fmaxf(acc[ncol][r] + bs[ncol], 0.f) * wf[ncol];
            partial += __shfl_xor(partial, 1);
            partial += __shfl_xor(partial, 2);
            partial += __shfl_xor(partial, 4);
            partial += __shfl_xor(partial, 8);
            if (m == 0 && node < NN) out_f32[node] = partial + bfc[0];
        }
    }
}

extern "C" void kernel_launch(void* const* d_in, const int* in_sizes, int n_in,
                              void* d_out, int out_size, void* d_ws, size_t ws_size,
                              hipStream_t stream) {
    const float* x   = (const float*)d_in[0];
    const int*   ei  = (const int*)d_in[1];
    const float* Wl1 = (const float*)d_in[2];
    const float* bl1 = (const float*)d_in[3];
    const float* Wr1 = (const float*)d_in[4];
    const float* Wl2 = (const float*)d_in[5];
    const float* bl2 = (const float*)d_in[6];
    const float* Wr2 = (const float*)d_in[7];
    const float* Wfc = (const float*)d_in[8];
    const float* bfc = (const float*)d_in[9];
    float* out = (float*)d_out;

    const int* srcp = ei;       // edge_index[0]
    const int* dstp = ei + NE;  // edge_index[1]

    char* p = (char*)d_ws;
    auto carve = [&](size_t bytes) {
        char* q = p;
        p += (bytes + 255) & ~size_t(255);
        return q;
    };
    int*            offsets = (int*)carve((size_t)(NN + 1) * 4);
    float*          inv_deg = (float*)carve((size_t)NN * 4);
    int*            ssrc    = (int*)carve((size_t)NE * 4);
    unsigned short* xh      = (unsigned short*)carve((size_t)NN * 64 * 2);
    unsigned short* h1h     = (unsigned short*)carve((size_t)NN * 64 * 2);
    unsigned short* wt1     = (unsigned short*)carve(64 * 128 * 2);
    unsigned short* wt2     = (unsigned short*)carve(64 * 128 * 2);
    unsigned int*   pairs   = (unsigned int*)carve((size_t)NE * 4);
    int*            hist    = (int*)carve((size_t)P1B * NBUCK * 4);   // [slice][bucket], 1.6 MB
    int*            total   = (int*)carve((size_t)NBUCK * 4);

    const int tile = (NN + 31) / 32;  // 3125 blocks of 32 nodes

    // graph build: 4 launches, no memset, no global atomics (R3: +50us), row-contiguous hist
    // (R5: column-layout hist was the regression; R7: merged sort-into-fused was the regression;
    // R8: widen grid-starved csr to 1024 threads (-10us); R9: colscan widen neutral;
    // R10: XCD-affine slice remap in scatter (-7us); R11: XCD-affine bucket remap in colscan).
    k_hist<<<P1B, 256, 0, stream>>>((const float4*)x, (ushort4*)xh,
                                    Wl1, Wr1, wt1, Wl2, Wr2, wt2, dstp, hist);
    k_colscan<<<NBUCK, 256, 0, stream>>>(hist, total, offsets);
    k_scatter<<<P1B, 256, 0, stream>>>(srcp, dstp, hist, total, pairs);
    k_bucket_csr<<<NBUCK, 1024, 0, stream>>>(pairs, total, ssrc, offsets, inv_deg);

    // layer 1: fused gather-aggregate (LDS) + MFMA dual GEMM -> h1h (f16)
    k_fused<false><<<tile, 256, 0, stream>>>((const uint4*)xh, ssrc, offsets, inv_deg,
                                             (const uint4*)wt1, bl1, Wfc, bfc, nullptr, h1h);
    // layer 2 + fused head
    k_fused<true><<<tile, 256, 0, stream>>>((const uint4*)h1h, ssrc, offsets, inv_deg,
                                            (const uint4*)wt2, bl2, Wfc, bfc, out, nullptr);
}